// Round 13
// baseline (181.208 us; speedup 1.0000x reference)
//
#include <hip/hip_runtime.h>
#include <stdint.h>

#define HH 352
#define WW 1216
#define HW (HH*WW)
#define BB 8
#define CLIPV 5.0f
#define MAXR 32

#define VR 44            // dest rows per band (352 = 8*44). R9-validated: vert
                         // is request-rate bound (~6.2 TB/s); VR=44 cut req
                         // bytes 269->216MB and vert 43.5->~33us as predicted.
#define NBAND (HH/VR)    // 8
#define PFD 8            // register prefetch depth (validated)
#define TOT (VR + MAXR)  // 76
#define RING 32          // circular removal ring (window depth, VR-independent)

// ============ vertical sliding-window scan, register-pipelined ============
// R9-validated structure: dir outputs in two LDS planes (no per-thread output
// arrays -> no register blow-up), 32-slot circular removal ring, PFD=8 pipe.
// NOTE: never add a min-waves launch bound (R2: forced VGPR cap -> scratch).
template<int DIR>
__device__ __forceinline__ void vert_scan(
    const int* __restrict__ m, const float* __restrict__ plog_v,
    const float* __restrict__ vp, const float* __restrict__ d,
    const int w, const int h0, const int lane,
    float2 (&obuf)[VR][64])
{
    const int hs   = DIR ? (h0 + VR - 1 + MAXR) : (h0 - MAXR);
    const int step = DIR ? -1 : 1;

    float rq_q[RING], rq_w[RING];             // circular removal ring (regs)
    int   r_mi[PFD];                          // register prefetch pipeline
    float r_pl[PFD], r_vv[PFD], r_dd[PFD];

    // ---- prologue: load first PFD iterations into the pipeline ----
    #pragma unroll
    for (int p = 0; p < PFD; ++p) {
        int hp = hs + p * step;
        int hc = min(max(hp, 0), HH-1);
        int idx = hc * WW + w;
        r_mi[p] = m[idx];
        r_pl[p] = plog_v[idx];
        r_vv[p] = vp[idx];
        r_dd[p] = d[idx];
    }

    float Q = 0.f, W = 0.f, EG = 1.f;         // EG = EA (dir0) or ED (dir1)
    int last_inv = hs - step;

    #pragma unroll
    for (int it = 0; it < TOT; ++it) {
        const int h  = hs + it * step;
        const int sl = it % PFD;

        int   mi  = ((unsigned)h < (unsigned)HH) ? r_mi[sl] : 0;
        float pl  = r_pl[sl];
        float vvx = r_vv[sl];
        float dd  = r_dd[sl];

        // refill this slot with iteration it+PFD (compile-time guard)
        if (it + PFD < TOT) {
            int hp = h + PFD * step;
            int hc = min(max(hp, 0), HH-1);
            int idx = hc * WW + w;
            r_mi[sl] = m[idx];
            r_pl[sl] = plog_v[idx];
            r_vv[sl] = vp[idx];
            r_dd[sl] = d[idx];
        }

        bool  res = (mi == 0);
        float g   = __expf(pl);
        float wt  = __expf(-fminf(vvx, CLIPV));
        float q, outw, outq;
        if constexpr (DIR == 0) {
            // output dest h first (window excludes src h)
            outw = W; outq = EG * Q;
            q = wt * dd * __builtin_amdgcn_rcpf(EG);
            // no res-zeroing of q/wt: ring values from a reset iteration are
            // provably never subtracted (alive==false after last_inv passes).
            Q  = res ? 0.f : (Q + q);
            W  = res ? 0.f : (W + wt);
            EG = res ? 1.f : (EG * g);
        } else {
            float EDh = EG * g;               // exp(D(h)), includes plog(h)
            outw = W; outq = Q * __builtin_amdgcn_rcpf(EDh);
            q = wt * dd * EDh;
            Q  = res ? 0.f : (Q + q);
            W  = res ? 0.f : (W + wt);
            EG = res ? 1.f : EDh;
        }
        last_inv = res ? h : last_inv;

        // removal BEFORE this iteration's ring store: at it in [32,VR) the
        // read slot (it-32)&31 aliases the store slot it&31 -- read first.
        if (it >= MAXR) {
            const int r = DIR ? (VR - 1 - (it - MAXR)) : (it - MAXR);
            obuf[r][lane] = make_float2(outw, outq);
            int s_out = h - MAXR * step;
            bool alive = DIR ? (s_out < last_inv) : (s_out > last_inv);
            Q -= alive ? rq_q[it & (RING-1)] : 0.f;
            W -= alive ? rq_w[it & (RING-1)] : 0.f;
        }
        if (it < VR) { rq_q[it & (RING-1)] = q; rq_w[it & (RING-1)] = wt; }
    }
}

__global__ __launch_bounds__(128) void crf_vert(
    const float* __restrict__ pred_log, const int* __restrict__ mask,
    const float* __restrict__ variance, const float* __restrict__ depth,
    float2* __restrict__ vq)
{
    __shared__ float2 obufA[VR][64];          // dir0 outputs (W, EA*Q)
    __shared__ float2 obufB[VR][64];          // dir1 outputs

    const int lane = threadIdx.x & 63;
    const int dir  = threadIdx.x >> 6;        // 0 = pos_h, 1 = neg_h
    const int id   = blockIdx.x;
    const int band = id & 7;                  // 8 bands == 8 XCDs
    const int seq  = id >> 3;
    const int wc   = seq % 19;
    const int b    = seq / 19;
    const int w    = wc * 64 + lane;

    const float* plog_v = pred_log + ((size_t)b*2 + 1) * HW;
    const int*   m  = mask     + (size_t)b*HW;
    const float* vp = variance + ((size_t)b*4 + (dir ? 3 : 2)) * HW;
    const float* d  = depth    + (size_t)b*HW;

    const int h0 = band * VR;

    if (dir == 0) {
        vert_scan<0>(m, plog_v, vp, d, w, h0, lane, obufA);
    } else {
        vert_scan<1>(m, plog_v, vp, d, w, h0, lane, obufB);
    }

    __syncthreads();
    // both waves merge + stream out (wave0: rows 0..21, wave1: rows 22..43)
    {
        float2* pvq = vq + (size_t)b*HW;
        const int w0c = wc * 64;
        const int rbeg = dir * (VR/2);
        #pragma unroll
        for (int r2 = 0; r2 < VR/2; ++r2) {
            const int r = rbeg + r2;
            float2 a = obufA[r][lane];
            float2 c = obufB[r][lane];
            pvq[(h0 + r) * WW + w0c + lane] = make_float2(a.x + c.x, a.y + c.y);
        }
    }
}

// ===================== horizontal: 2-row ILP wave-scan =====================
// R13: each block processes TWO independent rows (hA, hB=hA+22). horiz is
// dependency-latency bound (R11: halved instr count was NULL; all pipes <=50%)
// on two serial log2(64) shfl chains. Two rows per wave = two independent
// chains interleaved -> scheduler fills each chain's latency bubbles with the
// other row's work. LDS planes duplicated (39.8KB -> 4 blocks/CU = 16 w/CU).
__device__ __forceinline__ void h_pass1(
    int c, int lane, float pl, int mi, float dj, float v0, float v1,
    float* sG, float* sH, float* sI, float* sJ,
    float* sEt, float* sEti, float* sTw0, float* sTq0,
    unsigned long long* sBal,
    float& o_pAx, float& o_xw0, float& o_xq0, float& o_iw1, float& o_iq1)
{
    const int j = c*64 + lane;
    float wt0 = __expf(-fminf(v0, CLIPV));
    float wt1 = __expf(-fminf(v1, CLIPV));
    float ipA = pl;
    #pragma unroll
    for (int dlt = 1; dlt < 64; dlt <<= 1) {
        float u = __shfl_up(ipA, dlt, 64);
        if (lane >= dlt) ipA += u;
    }
    float pAx = ipA - pl;
    float S   = __shfl(ipA, 63, 64);
    float Einv = __expf(-pAx);
    float q0 = wt0 * dj * Einv;
    float q1 = wt1 * dj * Einv;
    float iw0 = wt0, iq0 = q0, iw1 = wt1, iq1 = q1;
    #pragma unroll
    for (int dlt = 1; dlt < 64; dlt <<= 1) {
        float a = __shfl_up(iw0, dlt, 64);
        float e = __shfl_up(iq0, dlt, 64);
        float f = __shfl_up(iw1, dlt, 64);
        float g = __shfl_up(iq1, dlt, 64);
        if (lane >= dlt) { iw0 += a; iq0 += e; iw1 += f; iq1 += g; }
    }
    sG[j] = iw0 - wt0;
    sH[j] = iq0 - q0;
    sI[j] = iw1;
    sJ[j] = iq1;
    unsigned long long bal = __ballot(mi == 0);
    if (lane == 63) {
        sEt[c]  = __expf(S);
        sEti[c] = __expf(-S);
        sTw0[c] = iw0;
        sTq0[c] = iq0;
    }
    if (lane == 0) sBal[c] = bal;
    o_pAx = pAx; o_xw0 = iw0 - wt0; o_xq0 = iq0 - q0;
    o_iw1 = iw1; o_iq1 = iq1;
}

__device__ __forceinline__ float h_pass2(
    int c, int lane, float pAx, float xw0, float xq0, float iw1, float iq1,
    const float* sG, const float* sH, const float* sI, const float* sJ,
    const float* sEt, const float* sEti, const float* sTw0, const float* sTq0,
    const unsigned long long* sBal,
    float2 vt, float mi_f, float dj, float lam)
{
    const int c0 = c*64;
    const int j  = c0 + lane;
    float E = __expf(pAx);
    unsigned long long balOwn = sBal[c];
    unsigned long long mb = balOwn & ((1ull << lane) - 1ull);
    int lm = mb ? (c0 + 63 - __builtin_clzll(mb)) : -1;
    if (c > 0 && lane < 32) {
        unsigned long long mp = sBal[c-1] & ~((1ull << (lane + 32)) - 1ull);
        if (mp) { int lm2 = c0 - 64 + 63 - __builtin_clzll(mp); lm = max(lm, lm2); }
    }
    int a0 = max(j - MAXR, lm + 1);
    float W0, Q0;
    if (a0 >= c0) {
        W0 = xw0 - sG[a0];
        Q0 = E * (xq0 - sH[a0]);
    } else {
        W0 = xw0 + (sTw0[c-1] - sG[a0]);
        Q0 = E * xq0 + E * sEt[c-1] * (sTq0[c-1] - sH[a0]);
    }
    int nm = 1 << 30;
    if (lane < 63) {
        unsigned long long nb = balOwn >> (lane + 1);
        if (nb) nm = j + 1 + __builtin_ctzll(nb);
    }
    if (c < 18 && lane >= 32) {
        unsigned long long nn = sBal[c+1] & ((1ull << (lane - 31)) - 1ull);
        if (nn) nm = min(nm, c0 + 64 + (int)__builtin_ctzll(nn));
    }
    int b1 = min(j + MAXR, nm - 1);
    b1 = min(b1, WW - 1);
    int endin = min(b1, c0 + 63);
    float W1 = 0.f, Q1 = 0.f;
    if (endin > j) {
        W1 = sI[endin] - iw1;
        Q1 = E * (sJ[endin] - iq1);
    }
    if (b1 > c0 + 63) {
        W1 += sI[b1];
        Q1 += E * sEti[c] * sJ[b1];
    }
    float totw  = W0 + W1 + vt.x;
    float totwd = Q0 + Q1 + vt.y;
    float lat = (totw > 0.f) ? (totwd / fmaxf(totw, 1e-12f)) : 0.f;
    lat *= mi_f;
    return (lat > 0.f) ? (dj * (1.f - lam) + lat * lam) : dj;
}

__global__ __launch_bounds__(256) void crf_horiz(
    const float* __restrict__ pred_log, const int* __restrict__ mask,
    const float* __restrict__ variance, const float* __restrict__ depth,
    const float* __restrict__ lam_p,
    const float2* __restrict__ vq,
    float* __restrict__ out)
{
    __shared__ float sGA[WW], sHA[WW], sIA[WW], sJA[WW];
    __shared__ float sGB[WW], sHB[WW], sIB[WW], sJB[WW];
    __shared__ float sEtA[19], sEtiA[19], sTw0A[19], sTq0A[19];
    __shared__ float sEtB[19], sEtiB[19], sTw0B[19], sTq0B[19];
    __shared__ unsigned long long sBalA[19], sBalB[19];

    const int tid  = threadIdx.x;
    const int lane = tid & 63;
    const int wv   = tid >> 6;
    const int i    = blockIdx.x;           // [0, 176)
    const int hA   = (i & 7) * 44 + (i >> 3);   // rows y in [0,22) of each 44-group
    const int hB   = hA + 22;                   // rows y in [22,44)
    const int b    = blockIdx.y;

    const float* plrowA = pred_log + (size_t)b*2*HW + hA*WW;
    const int*   mrowA  = mask     + (size_t)b*HW   + hA*WW;
    const float* v0rowA = variance + (size_t)b*4*HW + hA*WW;
    const float* v1rowA = v0rowA + HW;
    const float* drowA  = depth    + (size_t)b*HW   + hA*WW;
    const float2* vqrowA= vq  + (size_t)b*HW + hA*WW;
    float*       orowA  = out + (size_t)b*HW + hA*WW;

    const float* plrowB = plrowA + 22*WW;
    const int*   mrowB  = mrowA  + 22*WW;
    const float* v0rowB = v0rowA + 22*WW;
    const float* v1rowB = v1rowA + 22*WW;
    const float* drowB  = drowA  + 22*WW;
    const float2* vqrowB= vqrowA + 22*WW;
    float*       orowB  = orowA  + 22*WW;

    // ---- register staging: issue ALL global loads for BOTH rows up front ----
    float  lA_pl[5], lA_dj[5], lA_v0[5], lA_v1[5];
    float  lB_pl[5], lB_dj[5], lB_v0[5], lB_v1[5];
    int    lA_mi[5], lB_mi[5];
    float2 lA_vt[5], lB_vt[5];
    #pragma unroll
    for (int r = 0; r < 5; ++r) {
        int c = r*4 + wv;
        if (c < 19) {
            int j = c*64 + lane;
            lA_pl[r] = plrowA[j];  lB_pl[r] = plrowB[j];
            lA_mi[r] = mrowA[j];   lB_mi[r] = mrowB[j];
            lA_dj[r] = drowA[j];   lB_dj[r] = drowB[j];
            lA_v0[r] = v0rowA[j];  lB_v0[r] = v0rowB[j];
            lA_v1[r] = v1rowA[j];  lB_v1[r] = v1rowB[j];
            lA_vt[r] = vqrowA[j];  lB_vt[r] = vqrowB[j];
        }
    }

    float A_pAx[5], A_xw0[5], A_xq0[5], A_iw1[5], A_iq1[5];
    float B_pAx[5], B_xw0[5], B_xq0[5], B_iw1[5], B_iq1[5];

    #pragma unroll
    for (int r = 0; r < 5; ++r) {
        int c = r*4 + wv;
        if (c < 19) {
            h_pass1(c, lane, lA_pl[r], lA_mi[r], lA_dj[r], lA_v0[r], lA_v1[r],
                    sGA, sHA, sIA, sJA, sEtA, sEtiA, sTw0A, sTq0A, sBalA,
                    A_pAx[r], A_xw0[r], A_xq0[r], A_iw1[r], A_iq1[r]);
            h_pass1(c, lane, lB_pl[r], lB_mi[r], lB_dj[r], lB_v0[r], lB_v1[r],
                    sGB, sHB, sIB, sJB, sEtB, sEtiB, sTw0B, sTq0B, sBalB,
                    B_pAx[r], B_xw0[r], B_xq0[r], B_iw1[r], B_iq1[r]);
        }
    }
    __syncthreads();

    const float lam = lam_p[0];

    #pragma unroll
    for (int r = 0; r < 5; ++r) {
        int c = r*4 + wv;
        if (c < 19) {
            const int j = c*64 + lane;
            float oA = h_pass2(c, lane, A_pAx[r], A_xw0[r], A_xq0[r], A_iw1[r], A_iq1[r],
                               sGA, sHA, sIA, sJA, sEtA, sEtiA, sTw0A, sTq0A, sBalA,
                               lA_vt[r], (float)lA_mi[r], lA_dj[r], lam);
            float oB = h_pass2(c, lane, B_pAx[r], B_xw0[r], B_xq0[r], B_iw1[r], B_iq1[r],
                               sGB, sHB, sIB, sJB, sEtB, sEtiB, sTw0B, sTq0B, sBalB,
                               lB_vt[r], (float)lB_mi[r], lB_dj[r], lam);
            orowA[j] = oA;
            orowB[j] = oB;
        }
    }
}

// ===================== fallback (validated R2 monolithic) =====================
#define BWF 256
#define PADF 32
#define LWF (BWF + 2*PADF)

__global__ __launch_bounds__(256) void crf_fallback(
    const float* __restrict__ pred_log, const int* __restrict__ mask,
    const float* __restrict__ variance, const float* __restrict__ depth,
    const float* __restrict__ lam_p, float* __restrict__ out)
{
    __shared__ float s_m[LWF], s_wt0[LWF], s_wt1[LWF], s_gh[LWF], s_ghi[LWF], s_d[LWF];
    const int t  = threadIdx.x;
    const int i  = blockIdx.x;
    const int h  = (i & 7) * 44 + (i >> 3);
    const int w0 = blockIdx.y * BWF;
    const int b  = blockIdx.z;
    const float* plog_h = pred_log + (size_t)b * 2 * HW;
    const float* plog_v = plog_h + HW;
    const int*   m      = mask   + (size_t)b * HW;
    const float* v0     = variance + (size_t)b * 4 * HW;
    const float* v1     = v0 + HW;
    const float* v2     = v0 + 2 * HW;
    const float* v3     = v0 + 3 * HW;
    const float* d      = depth + (size_t)b * HW;
    for (int j = t; j < LWF; j += BWF) {
        int gw = w0 - PADF + j;
        float mf=0.f, wt0=0.f, wt1=0.f, gh=1.f, ghi=1.f, dd=0.f;
        if (gw >= 0 && gw < WW) {
            int idx = h * WW + gw;
            mf = (float)m[idx];
            float pl = plog_h[idx];
            gh = __expf(pl); ghi = __expf(-pl);
            wt0 = __expf(-fminf(v0[idx], CLIPV));
            wt1 = __expf(-fminf(v1[idx], CLIPV));
            dd = d[idx];
        }
        s_m[j]=mf; s_wt0[j]=wt0; s_wt1[j]=wt1; s_gh[j]=gh; s_ghi[j]=ghi; s_d[j]=dd;
    }
    __syncthreads();
    const int w = w0 + t;
    if (w >= WW) return;
    const int c = t + PADF;
    float totw = 0.f, totwd = 0.f;
    { float e=1.f, valid=1.f;
      #pragma unroll 8
      for (int k=1;k<=MAXR;++k){int s=c-k; valid*=s_m[s]; e*=s_gh[s];
        float wgt=s_wt0[s]*valid; totw+=wgt; totwd+=wgt*e*s_d[s];} }
    { float e=1.f, valid=1.f;
      #pragma unroll 8
      for (int k=1;k<=MAXR;++k){int s=c+k; e*=s_ghi[s-1]; valid*=s_m[s];
        float wgt=s_wt1[s]*valid; totw+=wgt; totwd+=wgt*e*s_d[s];} }
    { const int kup=min(MAXR,h); float e=1.f, valid=1.f;
      #pragma unroll 4
      for (int k=1;k<=kup;++k){int idx=(h-k)*WW+w; valid*=(float)m[idx];
        e*=__expf(plog_v[idx]); float wgt=__expf(-fminf(v2[idx],CLIPV))*valid;
        totw+=wgt; totwd+=wgt*e*d[idx];} }
    { const int kdn=min(MAXR,HH-1-h); float e=1.f, valid=1.f;
      #pragma unroll 4
      for (int k=1;k<=kdn;++k){int idx=(h+k)*WW+w; e*=__expf(-plog_v[idx-WW]);
        valid*=(float)m[idx]; float wgt=__expf(-fminf(v3[idx],CLIPV))*valid;
        totw+=wgt; totwd+=wgt*e*d[idx];} }
    const int base = h * WW + w;
    float lat = (totw > 0.f) ? (totwd / fmaxf(totw, 1e-12f)) : 0.f;
    lat *= s_m[c];
    float lam = lam_p[0];
    float di  = s_d[c];
    out[(size_t)b * HW + base] = (lat > 0.f) ? (di * (1.f - lam) + lat * lam) : di;
}

extern "C" void kernel_launch(void* const* d_in, const int* in_sizes, int n_in,
                              void* d_out, int out_size, void* d_ws, size_t ws_size,
                              hipStream_t stream) {
    const float* pred_log = (const float*)d_in[0];
    const int*   mask     = (const int*)  d_in[1];
    const float* variance = (const float*)d_in[2];
    const float* depthin  = (const float*)d_in[3];
    const float* lam      = (const float*)d_in[4];
    float* out = (float*)d_out;

    const size_t need = (size_t)BB * HW * sizeof(float2);   // 27.4 MB
    if (ws_size >= need) {
        float2* vq = (float2*)d_ws;
        dim3 vgrid(19 * NBAND * BB, 1, 1);                  // 1216 blocks x 128 thr
        hipLaunchKernelGGL(crf_vert, vgrid, dim3(128), 0, stream,
                           pred_log, mask, variance, depthin, vq);
        dim3 hgrid(HH/2, BB);                               // 176 x 8, 2 rows/block
        hipLaunchKernelGGL(crf_horiz, hgrid, dim3(256), 0, stream,
                           pred_log, mask, variance, depthin, lam, vq, out);
    } else {
        dim3 fgrid(HH, (WW + BWF - 1) / BWF, BB);
        hipLaunchKernelGGL(crf_fallback, fgrid, dim3(BWF), 0, stream,
                           pred_log, mask, variance, depthin, lam, out);
    }
}

// Round 14
// 170.932 us; speedup vs baseline: 1.0601x; 1.0601x over previous
//
#include <hip/hip_runtime.h>
#include <stdint.h>

#define HH 352
#define WW 1216
#define HW (HH*WW)
#define BB 8
#define CLIPV 5.0f
#define MAXR 32

#define VR 44            // dest rows per band (352 = 8*44). R9-validated: vert
                         // is request-rate bound (~6.2 TB/s); VR=44 cut req
                         // bytes 269->216MB and vert 43.5->~33us as predicted.
#define NBAND (HH/VR)    // 8
#define PFD 8            // register prefetch depth (validated)
#define TOT (VR + MAXR)  // 76
#define RING 32          // circular removal ring (window depth, VR-independent)

// ============ vertical sliding-window scan, register-pipelined ============
// R9-validated structure: dir outputs in two LDS planes (no per-thread output
// arrays -> no register blow-up), 32-slot circular removal ring, PFD=8 pipe.
// NOTE: never add a min-waves launch bound (R2: forced VGPR cap -> scratch).
template<int DIR>
__device__ __forceinline__ void vert_scan(
    const int* __restrict__ m, const float* __restrict__ plog_v,
    const float* __restrict__ vp, const float* __restrict__ d,
    const int w, const int h0, const int lane,
    float2 (&obuf)[VR][64])
{
    const int hs   = DIR ? (h0 + VR - 1 + MAXR) : (h0 - MAXR);
    const int step = DIR ? -1 : 1;

    float rq_q[RING], rq_w[RING];             // circular removal ring (regs)
    int   r_mi[PFD];                          // register prefetch pipeline
    float r_pl[PFD], r_vv[PFD], r_dd[PFD];

    // ---- prologue: load first PFD iterations into the pipeline ----
    #pragma unroll
    for (int p = 0; p < PFD; ++p) {
        int hp = hs + p * step;
        int hc = min(max(hp, 0), HH-1);
        int idx = hc * WW + w;
        r_mi[p] = m[idx];
        r_pl[p] = plog_v[idx];
        r_vv[p] = vp[idx];
        r_dd[p] = d[idx];
    }

    float Q = 0.f, W = 0.f, EG = 1.f;         // EG = EA (dir0) or ED (dir1)
    int last_inv = hs - step;

    #pragma unroll
    for (int it = 0; it < TOT; ++it) {
        const int h  = hs + it * step;
        const int sl = it % PFD;

        int   mi  = ((unsigned)h < (unsigned)HH) ? r_mi[sl] : 0;
        float pl  = r_pl[sl];
        float vvx = r_vv[sl];
        float dd  = r_dd[sl];

        // refill this slot with iteration it+PFD (compile-time guard)
        if (it + PFD < TOT) {
            int hp = h + PFD * step;
            int hc = min(max(hp, 0), HH-1);
            int idx = hc * WW + w;
            r_mi[sl] = m[idx];
            r_pl[sl] = plog_v[idx];
            r_vv[sl] = vp[idx];
            r_dd[sl] = d[idx];
        }

        bool  res = (mi == 0);
        float g   = __expf(pl);
        float wt  = __expf(-fminf(vvx, CLIPV));
        float q, outw, outq;
        if constexpr (DIR == 0) {
            // output dest h first (window excludes src h)
            outw = W; outq = EG * Q;
            q = wt * dd * __builtin_amdgcn_rcpf(EG);
            // no res-zeroing of q/wt: ring values from a reset iteration are
            // provably never subtracted (alive==false after last_inv passes).
            Q  = res ? 0.f : (Q + q);
            W  = res ? 0.f : (W + wt);
            EG = res ? 1.f : (EG * g);
        } else {
            float EDh = EG * g;               // exp(D(h)), includes plog(h)
            outw = W; outq = Q * __builtin_amdgcn_rcpf(EDh);
            q = wt * dd * EDh;
            Q  = res ? 0.f : (Q + q);
            W  = res ? 0.f : (W + wt);
            EG = res ? 1.f : EDh;
        }
        last_inv = res ? h : last_inv;

        // removal BEFORE this iteration's ring store: at it in [32,VR) the
        // read slot (it-32)&31 aliases the store slot it&31 -- read first.
        if (it >= MAXR) {
            const int r = DIR ? (VR - 1 - (it - MAXR)) : (it - MAXR);
            obuf[r][lane] = make_float2(outw, outq);
            int s_out = h - MAXR * step;
            bool alive = DIR ? (s_out < last_inv) : (s_out > last_inv);
            Q -= alive ? rq_q[it & (RING-1)] : 0.f;
            W -= alive ? rq_w[it & (RING-1)] : 0.f;
        }
        if (it < VR) { rq_q[it & (RING-1)] = q; rq_w[it & (RING-1)] = wt; }
    }
}

__global__ __launch_bounds__(128) void crf_vert(
    const float* __restrict__ pred_log, const int* __restrict__ mask,
    const float* __restrict__ variance, const float* __restrict__ depth,
    float2* __restrict__ vq)
{
    __shared__ float2 obufA[VR][64];          // dir0 outputs (W, EA*Q)
    __shared__ float2 obufB[VR][64];          // dir1 outputs

    const int lane = threadIdx.x & 63;
    const int dir  = threadIdx.x >> 6;        // 0 = pos_h, 1 = neg_h
    const int id   = blockIdx.x;
    const int band = id & 7;                  // 8 bands == 8 XCDs
    const int seq  = id >> 3;
    const int wc   = seq % 19;
    const int b    = seq / 19;
    const int w    = wc * 64 + lane;

    const float* plog_v = pred_log + ((size_t)b*2 + 1) * HW;
    const int*   m  = mask     + (size_t)b*HW;
    const float* vp = variance + ((size_t)b*4 + (dir ? 3 : 2)) * HW;
    const float* d  = depth    + (size_t)b*HW;

    const int h0 = band * VR;

    if (dir == 0) {
        vert_scan<0>(m, plog_v, vp, d, w, h0, lane, obufA);
    } else {
        vert_scan<1>(m, plog_v, vp, d, w, h0, lane, obufB);
    }

    __syncthreads();
    // both waves merge + stream out (wave0: rows 0..21, wave1: rows 22..43)
    {
        float2* pvq = vq + (size_t)b*HW;
        const int w0c = wc * 64;
        const int rbeg = dir * (VR/2);
        #pragma unroll
        for (int r2 = 0; r2 < VR/2; ++r2) {
            const int r = rbeg + r2;
            float2 a = obufA[r][lane];
            float2 c = obufB[r][lane];
            pvq[(h0 + r) * WW + w0c + lane] = make_float2(a.x + c.x, a.y + c.y);
        }
    }
}

// ===================== horizontal: chunk-anchored wave-scan =====================
// R10-validated: explicit register staging. The pre-R10 codegen had VGPR=36 --
// too few for the per-r arrays, so each of the 5 r-iterations serialized
// {6 loads -> full mem latency -> 400cy shfl chain}. Staging ALL global loads
// (incl. vq) into statically-indexed register arrays collapses 5 load-stalls
// into 1. R11 (128-wide chunks, halved instr count) was NULL and R13 (2-row
// ILP) was NEGATIVE (LDS x2 -> occupancy 52->24%): horiz is dependency-latency
// bound at its LDS-capped occupancy; this structure is its optimum.
__global__ __launch_bounds__(256) void crf_horiz(
    const float* __restrict__ pred_log, const int* __restrict__ mask,
    const float* __restrict__ variance, const float* __restrict__ depth,
    const float* __restrict__ lam_p,
    const float2* __restrict__ vq,
    float* __restrict__ out)
{
    __shared__ float sG[WW];
    __shared__ float sH[WW];
    __shared__ float sI[WW];
    __shared__ float sJ[WW];
    __shared__ float sEt[19], sEti[19], sTw0[19], sTq0[19];
    __shared__ unsigned long long sBal[19];

    const int tid  = threadIdx.x;
    const int lane = tid & 63;
    const int wv   = tid >> 6;
    const int i    = blockIdx.x;
    const int h    = (i & 7) * 44 + (i >> 3);
    const int b    = blockIdx.y;

    const float* plrow = pred_log + (size_t)b*2*HW + h*WW;
    const int*   mrow  = mask     + (size_t)b*HW   + h*WW;
    const float* v0row = variance + (size_t)b*4*HW + h*WW;
    const float* v1row = v0row + HW;
    const float* drow  = depth    + (size_t)b*HW   + h*WW;
    const float2* vqrow= vq  + (size_t)b*HW + h*WW;
    float*       orow  = out + (size_t)b*HW + h*WW;

    // ---- register staging: issue ALL global loads up front ----
    float  l_pl[5], l_dj[5], l_v0[5], l_v1[5];
    int    l_mi[5];
    float2 l_vt[5];
    #pragma unroll
    for (int r = 0; r < 5; ++r) {
        int c = r*4 + wv;
        if (c < 19) {
            int j = c*64 + lane;
            l_pl[r] = plrow[j];
            l_mi[r] = mrow[j];
            l_dj[r] = drow[j];
            l_v0[r] = v0row[j];
            l_v1[r] = v1row[j];
            l_vt[r] = vqrow[j];
        }
    }

    float l_pAx[5], l_xw0[5], l_xq0[5], l_iw1[5], l_iq1[5];

    #pragma unroll
    for (int r = 0; r < 5; ++r) {
        int c = r*4 + wv;
        if (c < 19) {
            int j = c*64 + lane;
            float pl  = l_pl[r];
            int   mi  = l_mi[r];
            float dj  = l_dj[r];
            float wt0 = __expf(-fminf(l_v0[r], CLIPV));
            float wt1 = __expf(-fminf(l_v1[r], CLIPV));
            float ipA = pl;
            #pragma unroll
            for (int dlt = 1; dlt < 64; dlt <<= 1) {
                float u = __shfl_up(ipA, dlt, 64);
                if (lane >= dlt) ipA += u;
            }
            float pAx = ipA - pl;
            float S   = __shfl(ipA, 63, 64);
            float Einv = __expf(-pAx);
            float q0 = wt0 * dj * Einv;
            float q1 = wt1 * dj * Einv;
            float iw0 = wt0, iq0 = q0, iw1 = wt1, iq1 = q1;
            #pragma unroll
            for (int dlt = 1; dlt < 64; dlt <<= 1) {
                float a = __shfl_up(iw0, dlt, 64);
                float e = __shfl_up(iq0, dlt, 64);
                float f = __shfl_up(iw1, dlt, 64);
                float g = __shfl_up(iq1, dlt, 64);
                if (lane >= dlt) { iw0 += a; iq0 += e; iw1 += f; iq1 += g; }
            }
            sG[j] = iw0 - wt0;
            sH[j] = iq0 - q0;
            sI[j] = iw1;
            sJ[j] = iq1;
            unsigned long long bal = __ballot(mi == 0);
            if (lane == 63) {
                sEt[c]  = __expf(S);
                sEti[c] = __expf(-S);
                sTw0[c] = iw0;
                sTq0[c] = iq0;
            }
            if (lane == 0) sBal[c] = bal;
            l_pAx[r] = pAx; l_xw0[r] = iw0 - wt0; l_xq0[r] = iq0 - q0;
            l_iw1[r] = iw1; l_iq1[r] = iq1;
        }
    }
    __syncthreads();

    const float lam = lam_p[0];

    #pragma unroll
    for (int r = 0; r < 5; ++r) {
        int c = r*4 + wv;
        if (c < 19) {
            const int c0 = c*64;
            const int j  = c0 + lane;
            float E = __expf(l_pAx[r]);
            unsigned long long balOwn = sBal[c];
            unsigned long long mb = balOwn & ((1ull << lane) - 1ull);
            int lm = mb ? (c0 + 63 - __builtin_clzll(mb)) : -1;
            if (c > 0 && lane < 32) {
                unsigned long long mp = sBal[c-1] & ~((1ull << (lane + 32)) - 1ull);
                if (mp) { int lm2 = c0 - 64 + 63 - __builtin_clzll(mp); lm = max(lm, lm2); }
            }
            int a0 = max(j - MAXR, lm + 1);
            float W0, Q0;
            if (a0 >= c0) {
                W0 = l_xw0[r] - sG[a0];
                Q0 = E * (l_xq0[r] - sH[a0]);
            } else {
                W0 = l_xw0[r] + (sTw0[c-1] - sG[a0]);
                Q0 = E * l_xq0[r] + E * sEt[c-1] * (sTq0[c-1] - sH[a0]);
            }
            int nm = 1 << 30;
            if (lane < 63) {
                unsigned long long nb = balOwn >> (lane + 1);
                if (nb) nm = j + 1 + __builtin_ctzll(nb);
            }
            if (c < 18 && lane >= 32) {
                unsigned long long nn = sBal[c+1] & ((1ull << (lane - 31)) - 1ull);
                if (nn) nm = min(nm, c0 + 64 + (int)__builtin_ctzll(nn));
            }
            int b1 = min(j + MAXR, nm - 1);
            b1 = min(b1, WW - 1);
            int endin = min(b1, c0 + 63);
            float W1 = 0.f, Q1 = 0.f;
            if (endin > j) {
                W1 = sI[endin] - l_iw1[r];
                Q1 = E * (sJ[endin] - l_iq1[r]);
            }
            if (b1 > c0 + 63) {
                W1 += sI[b1];
                Q1 += E * sEti[c] * sJ[b1];
            }
            float2 vt = l_vt[r];
            float totw  = W0 + W1 + vt.x;
            float totwd = Q0 + Q1 + vt.y;
            float lat = (totw > 0.f) ? (totwd / fmaxf(totw, 1e-12f)) : 0.f;
            lat *= (float)l_mi[r];
            float dj = l_dj[r];
            orow[j] = (lat > 0.f) ? (dj * (1.f - lam) + lat * lam) : dj;
        }
    }
}

// ===================== fallback (validated R2 monolithic) =====================
#define BWF 256
#define PADF 32
#define LWF (BWF + 2*PADF)

__global__ __launch_bounds__(256) void crf_fallback(
    const float* __restrict__ pred_log, const int* __restrict__ mask,
    const float* __restrict__ variance, const float* __restrict__ depth,
    const float* __restrict__ lam_p, float* __restrict__ out)
{
    __shared__ float s_m[LWF], s_wt0[LWF], s_wt1[LWF], s_gh[LWF], s_ghi[LWF], s_d[LWF];
    const int t  = threadIdx.x;
    const int i  = blockIdx.x;
    const int h  = (i & 7) * 44 + (i >> 3);
    const int w0 = blockIdx.y * BWF;
    const int b  = blockIdx.z;
    const float* plog_h = pred_log + (size_t)b * 2 * HW;
    const float* plog_v = plog_h + HW;
    const int*   m      = mask   + (size_t)b * HW;
    const float* v0     = variance + (size_t)b * 4 * HW;
    const float* v1     = v0 + HW;
    const float* v2     = v0 + 2 * HW;
    const float* v3     = v0 + 3 * HW;
    const float* d      = depth + (size_t)b * HW;
    for (int j = t; j < LWF; j += BWF) {
        int gw = w0 - PADF + j;
        float mf=0.f, wt0=0.f, wt1=0.f, gh=1.f, ghi=1.f, dd=0.f;
        if (gw >= 0 && gw < WW) {
            int idx = h * WW + gw;
            mf = (float)m[idx];
            float pl = plog_h[idx];
            gh = __expf(pl); ghi = __expf(-pl);
            wt0 = __expf(-fminf(v0[idx], CLIPV));
            wt1 = __expf(-fminf(v1[idx], CLIPV));
            dd = d[idx];
        }
        s_m[j]=mf; s_wt0[j]=wt0; s_wt1[j]=wt1; s_gh[j]=gh; s_ghi[j]=ghi; s_d[j]=dd;
    }
    __syncthreads();
    const int w = w0 + t;
    if (w >= WW) return;
    const int c = t + PADF;
    float totw = 0.f, totwd = 0.f;
    { float e=1.f, valid=1.f;
      #pragma unroll 8
      for (int k=1;k<=MAXR;++k){int s=c-k; valid*=s_m[s]; e*=s_gh[s];
        float wgt=s_wt0[s]*valid; totw+=wgt; totwd+=wgt*e*s_d[s];} }
    { float e=1.f, valid=1.f;
      #pragma unroll 8
      for (int k=1;k<=MAXR;++k){int s=c+k; e*=s_ghi[s-1]; valid*=s_m[s];
        float wgt=s_wt1[s]*valid; totw+=wgt; totwd+=wgt*e*s_d[s];} }
    { const int kup=min(MAXR,h); float e=1.f, valid=1.f;
      #pragma unroll 4
      for (int k=1;k<=kup;++k){int idx=(h-k)*WW+w; valid*=(float)m[idx];
        e*=__expf(plog_v[idx]); float wgt=__expf(-fminf(v2[idx],CLIPV))*valid;
        totw+=wgt; totwd+=wgt*e*d[idx];} }
    { const int kdn=min(MAXR,HH-1-h); float e=1.f, valid=1.f;
      #pragma unroll 4
      for (int k=1;k<=kdn;++k){int idx=(h+k)*WW+w; e*=__expf(-plog_v[idx-WW]);
        valid*=(float)m[idx]; float wgt=__expf(-fminf(v3[idx],CLIPV))*valid;
        totw+=wgt; totwd+=wgt*e*d[idx];} }
    const int base = h * WW + w;
    float lat = (totw > 0.f) ? (totwd / fmaxf(totw, 1e-12f)) : 0.f;
    lat *= s_m[c];
    float lam = lam_p[0];
    float di  = s_d[c];
    out[(size_t)b * HW + base] = (lat > 0.f) ? (di * (1.f - lam) + lat * lam) : di;
}

extern "C" void kernel_launch(void* const* d_in, const int* in_sizes, int n_in,
                              void* d_out, int out_size, void* d_ws, size_t ws_size,
                              hipStream_t stream) {
    const float* pred_log = (const float*)d_in[0];
    const int*   mask     = (const int*)  d_in[1];
    const float* variance = (const float*)d_in[2];
    const float* depthin  = (const float*)d_in[3];
    const float* lam      = (const float*)d_in[4];
    float* out = (float*)d_out;

    const size_t need = (size_t)BB * HW * sizeof(float2);   // 27.4 MB
    if (ws_size >= need) {
        float2* vq = (float2*)d_ws;
        dim3 vgrid(19 * NBAND * BB, 1, 1);                  // 1216 blocks x 128 thr
        hipLaunchKernelGGL(crf_vert, vgrid, dim3(128), 0, stream,
                           pred_log, mask, variance, depthin, vq);
        dim3 hgrid(HH, BB);
        hipLaunchKernelGGL(crf_horiz, hgrid, dim3(256), 0, stream,
                           pred_log, mask, variance, depthin, lam, vq, out);
    } else {
        dim3 fgrid(HH, (WW + BWF - 1) / BWF, BB);
        hipLaunchKernelGGL(crf_fallback, fgrid, dim3(BWF), 0, stream,
                           pred_log, mask, variance, depthin, lam, out);
    }
}